// Round 6
// baseline (28.058 us; speedup 1.0000x reference)
//
#include <hip/hip_runtime.h>

typedef __attribute__((ext_vector_type(8))) short    short8;   // 8 x bf16 (MFMA A/B frag)
typedef __attribute__((ext_vector_type(4))) float    f32x4;    // MFMA C/D frag
typedef __attribute__((ext_vector_type(4))) unsigned uint4_;
typedef __attribute__((ext_vector_type(2))) unsigned uint2_;

#define HW     16000
#define WWID   200
#define NPARAM 8513
// raw param offsets: w0[64][66] @0, w1[64][64] @4224, w2 @8320, b0 @8384, b1 @8448, b2 @8512

__device__ __forceinline__ unsigned f2bf(float f) {   // RNE fp32 -> bf16
    unsigned u = __builtin_bit_cast(unsigned, f);
    return (u + 0x7FFFu + ((u >> 16) & 1u)) >> 16;
}
__device__ __forceinline__ unsigned pkbf2(float a, float b) {
    return f2bf(a) | (f2bf(b) << 16);
}
__device__ __forceinline__ short8 mk8(unsigned a, unsigned b, unsigned c, unsigned d) {
    uint4_ u; u.x = a; u.y = b; u.z = c; u.w = d;
    return __builtin_bit_cast(short8, u);
}

// block = 1024 threads (16 waves). Wave wid: inst = wid>>1 (0..7), kh = wid&1
// (output-k half: k in [kh*32, kh*32+32)). Each wave holds HALF an instance's
// weights in registers (~120 VGPR -> 4 waves/SIMD). Per 16-px slice:
//   L0 (6 MFMA, k-half) -> h0 halves exchanged via LDS dbuf -> barrier ->
//   L1 (4 MFMA, full c from both halves) -> partial v -> vpart LDS;
//   combine+store is pipelined one slice behind (reuses the same barrier).
// LDS: xt 64KB + h0 2x8x2KB = 32KB + vpart 2KB = 100352 B.
__global__ __launch_bounds__(1024, 4) void condlane_ksplit(
    const float* __restrict__ x,        // [N, 64, HW]
    const float* __restrict__ params,   // [M, 8513]
    float* __restrict__ out,            // [M, HW]
    int num_ins, int M_total)
{
    extern __shared__ char lds[];
    char*  xt     = lds;                          // 65536 B
    char*  h0base = lds + 65536;                  // 2 bufs * 8 inst * 2048 B
    float* vpart  = (float*)(lds + 65536 + 32768);// 2 bufs * 8 inst * 2 kh * 16 px

    const int tid  = threadIdx.x;
    const int lane = tid & 63;
    const int wid  = tid >> 6;          // 0..15
    const int inst = wid >> 1;          // 0..7
    const int kh   = wid & 1;           // output-k half
    const int n    = blockIdx.y;
    const int pxg0 = blockIdx.x * 256;
    const int g    = (lane >> 4) & 3;
    const int px16 = lane & 15;

    // ---- stage x tile: [256 px][128 ch] bf16, swizzle byte ^= (p&15)<<4 ----
    {
        const int p   = tid & 255;
        const int sel = tid >> 8;       // 0..3, each stages 16 fp32 channels
        const int pc  = min(pxg0 + p, HW - 1);
        const float* xp = x + (size_t)n * 64 * HW + pc;
        #pragma unroll
        for (int it = 0; it < 2; ++it) {
            int c0 = sel * 16 + it * 8;
            uint4_ d;
            d.x = pkbf2(xp[(size_t)(c0 + 0) * HW], xp[(size_t)(c0 + 1) * HW]);
            d.y = pkbf2(xp[(size_t)(c0 + 2) * HW], xp[(size_t)(c0 + 3) * HW]);
            d.z = pkbf2(xp[(size_t)(c0 + 4) * HW], xp[(size_t)(c0 + 5) * HW]);
            d.w = pkbf2(xp[(size_t)(c0 + 6) * HW], xp[(size_t)(c0 + 7) * HW]);
            int byte = (p * 256 + c0 * 2) ^ ((p & 15) << 4);
            *(uint4_*)(xt + byte) = d;
        }
        // constant K-channels 64..95: {lx, ly, 1, 0, ...}; sel s writes 16B at 128+s*16
        const int pg = pxg0 + p;        // values for pg>=HW never consumed
        float lx = (float)(pg % WWID) * (1.0f / WWID);
        float ly = (float)(pg / WWID) * (1.0f / WWID);   // source bug: also /W
        uint4_ cv;
        cv.x = (sel == 0) ? pkbf2(lx, ly)   : 0u;
        cv.y = (sel == 0) ? pkbf2(1.f, 0.f) : 0u;
        cv.z = 0u; cv.w = 0u;
        int byte = (p * 256 + 128 + sel * 16) ^ ((p & 15) << 4);
        *(uint4_*)(xt + byte) = cv;
    }

    // ---- per-wave (half-instance) weight gather into registers ----
    const int m  = n * num_ins + inst;
    const float* pm = params + (size_t)min(m, M_total - 1) * NPARAM;

    short8 w0f[3][2], w1f[2][2];
    #pragma unroll
    for (int kbl = 0; kbl < 2; ++kbl) {
        const int k = kh * 32 + kbl * 16 + px16;
        #pragma unroll
        for (int ch = 0; ch < 2; ++ch) {
            const float* s0 = pm + k * 66 + 2 + ch * 32 + g * 8;   // w0 x-cols
            w0f[ch][kbl] = mk8(pkbf2(s0[0], s0[1]), pkbf2(s0[2], s0[3]),
                               pkbf2(s0[4], s0[5]), pkbf2(s0[6], s0[7]));
            const float* s1 = pm + 4224 + k * 64 + ch * 32 + g * 8; // w1
            w1f[ch][kbl] = mk8(pkbf2(s1[0], s1[1]), pkbf2(s1[2], s1[3]),
                               pkbf2(s1[4], s1[5]), pkbf2(s1[6], s1[7]));
        }
        // K-channels 64..95 = {lx, ly, 1, 0...} -> cols {w00, w01, b0, 0...}
        float a = (g == 0) ? pm[k * 66 + 0] : 0.0f;
        float b = (g == 0) ? pm[k * 66 + 1] : 0.0f;
        float c = (g == 0) ? pm[8384 + k]   : 0.0f;
        w0f[2][kbl] = mk8(pkbf2(a, b), pkbf2(c, 0.0f), 0u, 0u);
    }
    f32x4 bias1[2], w2v[2];
    #pragma unroll
    for (int kbl = 0; kbl < 2; ++kbl)
        #pragma unroll
        for (int j = 0; j < 4; ++j) {
            bias1[kbl][j] = pm[8448 + kh * 32 + kbl * 16 + g * 4 + j];
            w2v[kbl][j]   = pm[8320 + kh * 32 + kbl * 16 + g * 4 + j];
        }
    const float b2 = pm[8512] - 2.19f;

    __syncthreads();   // xt ready

    const int  swzx = px16 << 4;
    const int  swzh = (px16 & 7) << 4;
    const bool do_store = (kh == 0) && (lane < 16) && (inst < num_ins);

    for (int s = 0; s < 16; ++s) {
        const int pxl = s * 16 + px16;
        // x B-frags (K=96)
        short8 xf[3];
        #pragma unroll
        for (int ch = 0; ch < 3; ++ch)
            xf[ch] = *(const short8*)(xt + ((pxl * 256 + ch * 64 + g * 16) ^ swzx));
        // layer 0 (k-half): 6 MFMA
        f32x4 acc0[2];
        #pragma unroll
        for (int kbl = 0; kbl < 2; ++kbl)
            #pragma unroll
            for (int j = 0; j < 4; ++j) acc0[kbl][j] = 0.f;
        #pragma unroll
        for (int ch = 0; ch < 3; ++ch)
            #pragma unroll
            for (int kbl = 0; kbl < 2; ++kbl)
                acc0[kbl] = __builtin_amdgcn_mfma_f32_16x16x32_bf16(w0f[ch][kbl], xf[ch], acc0[kbl], 0, 0, 0);
        // relu -> bf16 h0 (this wave's 32 c-rows), dbuf slot s&1
        char* hb = h0base + (s & 1) * 16384 + inst * 2048;
        #pragma unroll
        for (int kbl = 0; kbl < 2; ++kbl) {
            uint2_ pk;
            pk.x = pkbf2(fmaxf(acc0[kbl][0], 0.f), fmaxf(acc0[kbl][1], 0.f));
            pk.y = pkbf2(fmaxf(acc0[kbl][2], 0.f), fmaxf(acc0[kbl][3], 0.f));
            int c0 = kh * 32 + kbl * 16 + g * 4;
            int byte = (px16 * 128 + c0 * 2) ^ swzh;
            *(uint2_*)(hb + byte) = pk;
        }

        __syncthreads();   // h0[s] complete; vpart[s-1] complete

        // combine + store previous slice (pipelined)
        if (s > 0 && do_store) {
            const float* vp = vpart + ((s - 1) & 1) * 256 + inst * 32;
            float v = vp[lane] + vp[16 + lane];
            int pxg = pxg0 + (s - 1) * 16 + lane;
            if (pxg < HW) out[(size_t)m * HW + pxg] = v + b2;
        }

        // layer 1: full-c h0 (both halves), 4 MFMA into this wave's k-half
        short8 hf[2];
        #pragma unroll
        for (int ch = 0; ch < 2; ++ch)
            hf[ch] = *(const short8*)(hb + ((px16 * 128 + ch * 64 + g * 16) ^ swzh));
        f32x4 acc1[2];
        #pragma unroll
        for (int kbl = 0; kbl < 2; ++kbl) acc1[kbl] = bias1[kbl];
        #pragma unroll
        for (int ch = 0; ch < 2; ++ch)
            #pragma unroll
            for (int kbl = 0; kbl < 2; ++kbl)
                acc1[kbl] = __builtin_amdgcn_mfma_f32_16x16x32_bf16(w1f[ch][kbl], hf[ch], acc1[kbl], 0, 0, 0);
        // layer 2 partial (this k-half), wave-internal reduce over g-groups
        float v = 0.f;
        #pragma unroll
        for (int kbl = 0; kbl < 2; ++kbl)
            #pragma unroll
            for (int j = 0; j < 4; ++j)
                v += w2v[kbl][j] * fmaxf(acc1[kbl][j], 0.f);
        v += __shfl_xor(v, 16);
        v += __shfl_xor(v, 32);
        if (lane < 16)
            vpart[(s & 1) * 256 + inst * 32 + kh * 16 + lane] = v;
    }

    __syncthreads();   // vpart[15] ready
    if (do_store) {
        const float* vp = vpart + (15 & 1) * 256 + inst * 32;
        float v = vp[lane] + vp[16 + lane];
        int pxg = pxg0 + 15 * 16 + lane;
        if (pxg < HW) out[(size_t)m * HW + pxg] = v + b2;
    }
}

extern "C" void kernel_launch(void* const* d_in, const int* in_sizes, int n_in,
                              void* d_out, int out_size, void* d_ws, size_t ws_size,
                              hipStream_t stream) {
    const float* x      = (const float*)d_in[0];
    const float* params = (const float*)d_in[1];
    float* out          = (float*)d_out;

    const int N = in_sizes[0] / (64 * HW);   // 4
    const int M = in_sizes[1] / NPARAM;      // 32
    const int num_ins = M / N;               // 8

    dim3 grid((HW + 255) / 256, N);          // 63 x 4 = 252 blocks
    condlane_ksplit<<<grid, 1024, 100352, stream>>>(x, params, out, num_ins, M);
}